// Round 1
// baseline (1965.930 us; speedup 1.0000x reference)
//
#include <hip/hip_runtime.h>
#include <math.h>

#define B_SZ 32
#define L_SZ 32768
#define T_SZ 1024
#define PS_SZ 32
#define D_SZ 256

// ---------------- InstanceNorm over full series (ddof=1), one block per row ----------------
__global__ __launch_bounds__(1024) void norm_kernel(const float* __restrict__ x,
                                                    float* __restrict__ xn) {
  const int b = blockIdx.x;
  const int t = threadIdx.x;
  const float* row = x + (size_t)b * L_SZ;
  float* orow = xn + (size_t)b * L_SZ;
  float v[32];
  float s = 0.f, ss = 0.f;
#pragma unroll
  for (int i = 0; i < 8; ++i) {
    float4 f = *(const float4*)&row[i * 4096 + t * 4];
    v[i * 4 + 0] = f.x; v[i * 4 + 1] = f.y; v[i * 4 + 2] = f.z; v[i * 4 + 3] = f.w;
    s += f.x + f.y + f.z + f.w;
    ss += f.x * f.x + f.y * f.y + f.z * f.z + f.w * f.w;
  }
#pragma unroll
  for (int off = 32; off >= 1; off >>= 1) {
    s += __shfl_down(s, off);
    ss += __shfl_down(ss, off);
  }
  __shared__ float red_s[16], red_ss[16];
  __shared__ float sh_mean, sh_inv;
  const int wid = t >> 6, lane = t & 63;
  if (lane == 0) { red_s[wid] = s; red_ss[wid] = ss; }
  __syncthreads();
  if (t == 0) {
    float S = 0.f, SS = 0.f;
    for (int i = 0; i < 16; ++i) { S += red_s[i]; SS += red_ss[i]; }
    float mean = S * (1.f / (float)L_SZ);
    float var = (SS - S * mean) * (1.f / (float)(L_SZ - 1));  // unbiased
    sh_mean = mean;
    sh_inv = 1.f / (sqrtf(var) + 1e-5f);                      // std + 1e-5, then divide
  }
  __syncthreads();
  const float mean = sh_mean, inv = sh_inv;
#pragma unroll
  for (int i = 0; i < 8; ++i) {
    float4 f;
    f.x = (v[i * 4 + 0] - mean) * inv;
    f.y = (v[i * 4 + 1] - mean) * inv;
    f.z = (v[i * 4 + 2] - mean) * inv;
    f.w = (v[i * 4 + 3] - mean) * inv;
    *(float4*)&orow[i * 4096 + t * 4] = f;
  }
}

// ---------------- Fold W_proj@W_qkv (rows 0..31) and b_proj@W_qkv+b_qkv (row 32) ----------------
__global__ void wc_kernel(const float* __restrict__ Wp, const float* __restrict__ bp,
                          const float* __restrict__ Wq, const float* __restrict__ bq,
                          float* __restrict__ Wcb) {
  int idx = blockIdx.x * 256 + threadIdx.x;
  if (idx >= 33 * 768) return;
  int p = idx / 768, j = idx % 768;
  const float* arow = (p < 32) ? (Wp + p * 256) : bp;
  float acc = (p < 32) ? 0.f : bq[j];
  for (int d = 0; d < 256; ++d) acc += arow[d] * Wq[d * 768 + j];
  Wcb[idx] = acc;
}

// ---------------- Generic fp32 GEMM + bias: C[M,N] = A[M,K]@B[K,N] + bias ----------------
// Requires M%64==0, K%16==0, N%4==0. 64x64 tile, 256 threads, 4x4 micro-tile.
__global__ __launch_bounds__(256) void gemm_bias(const float* __restrict__ A,
                                                 const float* __restrict__ Bm,
                                                 const float* __restrict__ bias,
                                                 float* __restrict__ C,
                                                 int M, int N, int K) {
  constexpr int BK = 16;
  __shared__ float As[BK][64 + 4];
  __shared__ float Bs[BK][64 + 4];
  const int t = threadIdx.x;
  const int row0 = blockIdx.y * 64;
  const int col0 = blockIdx.x * 64;
  const int tx = t & 15, ty = t >> 4;
  const int ar = t >> 2, ak = (t & 3) << 2;
  const int bk = t >> 4, bc = (t & 15) << 2;
  float acc[4][4] = {};
  for (int k0 = 0; k0 < K; k0 += BK) {
    float4 a4 = *(const float4*)&A[(size_t)(row0 + ar) * K + k0 + ak];
    float4 b4 = make_float4(0.f, 0.f, 0.f, 0.f);
    if (col0 + bc < N) b4 = *(const float4*)&Bm[(size_t)(k0 + bk) * N + col0 + bc];
    As[ak + 0][ar] = a4.x; As[ak + 1][ar] = a4.y; As[ak + 2][ar] = a4.z; As[ak + 3][ar] = a4.w;
    *(float4*)&Bs[bk][bc] = b4;
    __syncthreads();
#pragma unroll
    for (int k = 0; k < BK; ++k) {
      float4 av = *(const float4*)&As[k][ty << 2];
      float4 bv = *(const float4*)&Bs[k][tx << 2];
      acc[0][0] += av.x * bv.x; acc[0][1] += av.x * bv.y; acc[0][2] += av.x * bv.z; acc[0][3] += av.x * bv.w;
      acc[1][0] += av.y * bv.x; acc[1][1] += av.y * bv.y; acc[1][2] += av.y * bv.z; acc[1][3] += av.y * bv.w;
      acc[2][0] += av.z * bv.x; acc[2][1] += av.z * bv.y; acc[2][2] += av.z * bv.z; acc[2][3] += av.z * bv.w;
      acc[3][0] += av.w * bv.x; acc[3][1] += av.w * bv.y; acc[3][2] += av.w * bv.z; acc[3][3] += av.w * bv.w;
    }
    __syncthreads();
  }
  const int cc = col0 + (tx << 2);
  if (cc < N) {
    float4 bi = *(const float4*)&bias[cc];
#pragma unroll
    for (int i = 0; i < 4; ++i) {
      int r = row0 + (ty << 2) + i;
      float4 o = make_float4(acc[i][0] + bi.x, acc[i][1] + bi.y,
                             acc[i][2] + bi.z, acc[i][3] + bi.w);
      *(float4*)&C[(size_t)r * N + cc] = o;
    }
  }
}

// ---------------- Causal flash attention, fp32. qkv rows: [q(256) k(256) v(256)] ----------------
// grid (T/32, B), 256 threads. Per block: 32 query rows, stream K/V tiles of 32.
__global__ __launch_bounds__(256) void attn_kernel(const float* __restrict__ qkv,
                                                   float* __restrict__ out) {
  const int qtile = blockIdx.x;
  const int b = blockIdx.y;
  const int t = threadIdx.x;

  __shared__ float Qs[32][D_SZ + 4];
  __shared__ float Ks[32][D_SZ + 4];
  __shared__ float Vs[32][D_SZ + 4];
  __shared__ float Ss[32][36];

  const size_t rowbase = (size_t)b * T_SZ;
  const int q0 = qtile << 5;

  for (int idx = t; idx < 32 * 64; idx += 256) {
    int r = idx >> 6;
    int c = (idx & 63) << 2;
    *(float4*)&Qs[r][c] = *(const float4*)&qkv[(rowbase + q0 + r) * 768 + c];
  }

  const int r = t >> 3;            // PV row 0..31
  const int c0 = (t & 7) << 5;     // PV col group (32 cols)
  const int sr = (t >> 4) << 1;    // score rows sr, sr+1
  const int sc = (t & 15) << 1;    // score cols sc, sc+1
  const float scale = 0.0625f;     // 1/sqrt(256)

  float m_i = -1e30f, l_i = 0.f;
  float O[32];
#pragma unroll
  for (int i = 0; i < 32; ++i) O[i] = 0.f;

  for (int kt = 0; kt <= qtile; ++kt) {
    const int k0 = kt << 5;
    __syncthreads();  // prior iter's Vs reads done before overwrite
    for (int idx = t; idx < 32 * 64; idx += 256) {
      int rr = idx >> 6;
      int c = (idx & 63) << 2;
      const size_t g = (rowbase + k0 + rr) * 768;
      *(float4*)&Ks[rr][c] = *(const float4*)&qkv[g + 256 + c];
      *(float4*)&Vs[rr][c] = *(const float4*)&qkv[g + 512 + c];
    }
    __syncthreads();
    // 2x2 scores over D=256
    float s00 = 0.f, s01 = 0.f, s10 = 0.f, s11 = 0.f;
#pragma unroll 8
    for (int k = 0; k < D_SZ; k += 4) {
      float4 qa = *(const float4*)&Qs[sr][k];
      float4 qb = *(const float4*)&Qs[sr + 1][k];
      float4 ka = *(const float4*)&Ks[sc][k];
      float4 kb = *(const float4*)&Ks[sc + 1][k];
      s00 += qa.x * ka.x + qa.y * ka.y + qa.z * ka.z + qa.w * ka.w;
      s01 += qa.x * kb.x + qa.y * kb.y + qa.z * kb.z + qa.w * kb.w;
      s10 += qb.x * ka.x + qb.y * ka.y + qb.z * ka.z + qb.w * ka.w;
      s11 += qb.x * kb.x + qb.y * kb.y + qb.z * kb.z + qb.w * kb.w;
    }
    const int qi0 = q0 + sr, kj0 = k0 + sc;
    Ss[sr][sc]         = (kj0     <= qi0    ) ? s00 * scale : -1e30f;
    Ss[sr][sc + 1]     = (kj0 + 1 <= qi0    ) ? s01 * scale : -1e30f;
    Ss[sr + 1][sc]     = (kj0     <= qi0 + 1) ? s10 * scale : -1e30f;
    Ss[sr + 1][sc + 1] = (kj0 + 1 <= qi0 + 1) ? s11 * scale : -1e30f;
    __syncthreads();
    // online softmax + PV (all 8 threads of a row compute identical m/l state)
    float m_tile = -1e30f;
#pragma unroll
    for (int j = 0; j < 32; ++j) m_tile = fmaxf(m_tile, Ss[r][j]);
    const float m_new = fmaxf(m_i, m_tile);
    const float alpha = __expf(m_i - m_new);
#pragma unroll
    for (int i = 0; i < 32; ++i) O[i] *= alpha;
    float psum = 0.f;
    for (int j = 0; j < 32; ++j) {
      const float pj = __expf(Ss[r][j] - m_new);
      psum += pj;
#pragma unroll
      for (int c = 0; c < 32; c += 4) {
        float4 v = *(const float4*)&Vs[j][c0 + c];
        O[c + 0] += pj * v.x; O[c + 1] += pj * v.y;
        O[c + 2] += pj * v.z; O[c + 3] += pj * v.w;
      }
    }
    l_i = l_i * alpha + psum;
    m_i = m_new;
  }
  const float inv = 1.f / l_i;
#pragma unroll
  for (int c = 0; c < 32; c += 4) {
    float4 o = make_float4(O[c] * inv, O[c + 1] * inv, O[c + 2] * inv, O[c + 3] * inv);
    *(float4*)&out[(rowbase + q0 + r) * D_SZ + c0 + c] = o;
  }
}

// ---------------- Next-patch MSE ----------------
__global__ __launch_bounds__(256) void loss_kernel(const float* __restrict__ pred,
                                                   const float* __restrict__ xn,
                                                   float* __restrict__ lsum) {
  const int total = B_SZ * (T_SZ - 1) * PS_SZ;
  float acc = 0.f;
  for (int idx = blockIdx.x * blockDim.x + threadIdx.x; idx < total;
       idx += gridDim.x * blockDim.x) {
    int p = idx & 31;
    int rem = idx >> 5;
    int tt = rem % (T_SZ - 1);
    int b = rem / (T_SZ - 1);
    float pr = pred[((size_t)b * T_SZ + tt) * PS_SZ + p];
    float tg = xn[(size_t)b * L_SZ + (tt + 1) * PS_SZ + p];
    float d = pr - tg;
    acc += d * d;
  }
#pragma unroll
  for (int off = 32; off >= 1; off >>= 1) acc += __shfl_down(acc, off);
  __shared__ float red[4];
  const int lane = threadIdx.x & 63, wid = threadIdx.x >> 6;
  if (lane == 0) red[wid] = acc;
  __syncthreads();
  if (threadIdx.x == 0) atomicAdd(lsum, red[0] + red[1] + red[2] + red[3]);
}

__global__ void finalize_kernel(const float* __restrict__ lsum, float* __restrict__ out) {
  out[0] = lsum[0] * (1.f / (float)(B_SZ * (T_SZ - 1) * PS_SZ));
}

extern "C" void kernel_launch(void* const* d_in, const int* in_sizes, int n_in,
                              void* d_out, int out_size, void* d_ws, size_t ws_size,
                              hipStream_t stream) {
  const float* x      = (const float*)d_in[0];
  const float* W_proj = (const float*)d_in[1];
  const float* b_proj = (const float*)d_in[2];
  const float* W_qkv  = (const float*)d_in[3];
  const float* b_qkv  = (const float*)d_in[4];
  const float* W_out  = (const float*)d_in[5];
  const float* b_out  = (const float*)d_in[6];
  const float* W_head = (const float*)d_in[7];
  const float* b_head = (const float*)d_in[8];
  float* out = (float*)d_out;

  char* ws = (char*)d_ws;
  float* xn   = (float*)(ws);                              // [0, 4MB)
  float* qkv  = (float*)(ws + (4ull << 20));               // [4MB, 100MB)
  float* ao   = (float*)(ws + (100ull << 20));             // [100MB, 132MB)
  float* o2   = (float*)(ws + (4ull << 20));               // reuse qkv (dead after attn)
  float* pred = (float*)(ws + (36ull << 20));              // reuse qkv tail
  float* Wcb  = (float*)(ws + (132ull << 20));             // 33x768 folded weights+bias
  float* lsum = (float*)(ws + (132ull << 20) + 33ull * 768ull * 4ull);

  hipMemsetAsync(lsum, 0, sizeof(float), stream);
  norm_kernel<<<32, 1024, 0, stream>>>(x, xn);
  wc_kernel<<<(33 * 768 + 255) / 256, 256, 0, stream>>>(W_proj, b_proj, W_qkv, b_qkv, Wcb);
  // qkv = patches @ (W_proj@W_qkv) + folded bias  (the 12.9GF QKV GEMM collapses to 1.6GF)
  gemm_bias<<<dim3(12, 512), 256, 0, stream>>>(xn, Wcb, Wcb + 32 * 768, qkv, 32768, 768, 32);
  attn_kernel<<<dim3(32, 32), 256, 0, stream>>>(qkv, ao);
  gemm_bias<<<dim3(4, 512), 256, 0, stream>>>(ao, W_out, b_out, o2, 32768, 256, 256);
  gemm_bias<<<dim3(1, 512), 256, 0, stream>>>(o2, W_head, b_head, pred, 32768, 32, 256);
  loss_kernel<<<256, 256, 0, stream>>>(pred, xn, lsum);
  finalize_kernel<<<1, 1, 0, stream>>>(lsum, out);
}

// Round 2
// 381.717 us; speedup vs baseline: 5.1502x; 5.1502x over previous
//
#include <hip/hip_runtime.h>
#include <math.h>

#define B_SZ 32
#define L_SZ 32768
#define T_SZ 1024
#define PS_SZ 32
#define D_SZ 256

typedef float f32x4 __attribute__((ext_vector_type(4)));
typedef short s16x8 __attribute__((ext_vector_type(8)));
typedef unsigned short u16x8 __attribute__((ext_vector_type(8)));
typedef unsigned short u16x4 __attribute__((ext_vector_type(4)));

__device__ inline unsigned short f2bf(float f) {
  union { float f; unsigned int u; } v; v.f = f;
  unsigned int r = v.u + 0x7FFFu + ((v.u >> 16) & 1u);
  return (unsigned short)(r >> 16);
}

// ---------------- InstanceNorm over full series (ddof=1), one block per row ----------------
__global__ __launch_bounds__(1024) void norm_kernel(const float* __restrict__ x,
                                                    float* __restrict__ xn) {
  const int b = blockIdx.x;
  const int t = threadIdx.x;
  const float* row = x + (size_t)b * L_SZ;
  float* orow = xn + (size_t)b * L_SZ;
  float v[32];
  float s = 0.f, ss = 0.f;
#pragma unroll
  for (int i = 0; i < 8; ++i) {
    float4 f = *(const float4*)&row[i * 4096 + t * 4];
    v[i * 4 + 0] = f.x; v[i * 4 + 1] = f.y; v[i * 4 + 2] = f.z; v[i * 4 + 3] = f.w;
    s += f.x + f.y + f.z + f.w;
    ss += f.x * f.x + f.y * f.y + f.z * f.z + f.w * f.w;
  }
#pragma unroll
  for (int off = 32; off >= 1; off >>= 1) {
    s += __shfl_down(s, off);
    ss += __shfl_down(ss, off);
  }
  __shared__ float red_s[16], red_ss[16];
  __shared__ float sh_mean, sh_inv;
  const int wid = t >> 6, lane = t & 63;
  if (lane == 0) { red_s[wid] = s; red_ss[wid] = ss; }
  __syncthreads();
  if (t == 0) {
    float S = 0.f, SS = 0.f;
    for (int i = 0; i < 16; ++i) { S += red_s[i]; SS += red_ss[i]; }
    float mean = S * (1.f / (float)L_SZ);
    float var = (SS - S * mean) * (1.f / (float)(L_SZ - 1));
    sh_mean = mean;
    sh_inv = 1.f / (sqrtf(var) + 1e-5f);
  }
  __syncthreads();
  const float mean = sh_mean, inv = sh_inv;
#pragma unroll
  for (int i = 0; i < 8; ++i) {
    float4 f;
    f.x = (v[i * 4 + 0] - mean) * inv;
    f.y = (v[i * 4 + 1] - mean) * inv;
    f.z = (v[i * 4 + 2] - mean) * inv;
    f.w = (v[i * 4 + 3] - mean) * inv;
    *(float4*)&orow[i * 4096 + t * 4] = f;
  }
}

// ---------------- Fold W_proj@W_qkv (rows 0..31) and b_proj@W_qkv+b_qkv (row 32) ----------------
__global__ void wc_kernel(const float* __restrict__ Wp, const float* __restrict__ bp,
                          const float* __restrict__ Wq, const float* __restrict__ bq,
                          float* __restrict__ Wcb) {
  int idx = blockIdx.x * 256 + threadIdx.x;
  if (idx >= 33 * 768) return;
  int p = idx / 768, j = idx % 768;
  const float* arow = (p < 32) ? (Wp + p * 256) : bp;
  float acc = (p < 32) ? 0.f : bq[j];
  for (int d = 0; d < 256; ++d) acc += arow[d] * Wq[d * 768 + j];
  Wcb[idx] = acc;
}

// ---------------- qkv GEMM: [32768,32]@[32,768]+bias, bf16 outputs split q/k/v ----------------
// Q columns pre-scaled by 1/16 (exact pow2) so attention needs no score scaling.
__global__ __launch_bounds__(256) void gemm_qkv(const float* __restrict__ A,
                                                const float* __restrict__ Bm,
                                                const float* __restrict__ bias,
                                                unsigned short* __restrict__ Qb,
                                                unsigned short* __restrict__ Kb,
                                                unsigned short* __restrict__ Vf) {
  constexpr int BK = 16;
  constexpr int N = 768, K = 32;
  __shared__ float As[BK][64 + 4];
  __shared__ float Bs[BK][64 + 4];
  const int t = threadIdx.x;
  const int row0 = blockIdx.y * 64;
  const int col0 = blockIdx.x * 64;
  const int tx = t & 15, ty = t >> 4;
  const int ar = t >> 2, ak = (t & 3) << 2;
  const int bk = t >> 4, bc = (t & 15) << 2;
  float acc[4][4] = {};
  for (int k0 = 0; k0 < K; k0 += BK) {
    float4 a4 = *(const float4*)&A[(size_t)(row0 + ar) * K + k0 + ak];
    float4 b4 = *(const float4*)&Bm[(size_t)(k0 + bk) * N + col0 + bc];
    As[ak + 0][ar] = a4.x; As[ak + 1][ar] = a4.y; As[ak + 2][ar] = a4.z; As[ak + 3][ar] = a4.w;
    *(float4*)&Bs[bk][bc] = b4;
    __syncthreads();
#pragma unroll
    for (int k = 0; k < BK; ++k) {
      float4 av = *(const float4*)&As[k][ty << 2];
      float4 bv = *(const float4*)&Bs[k][tx << 2];
      acc[0][0] += av.x * bv.x; acc[0][1] += av.x * bv.y; acc[0][2] += av.x * bv.z; acc[0][3] += av.x * bv.w;
      acc[1][0] += av.y * bv.x; acc[1][1] += av.y * bv.y; acc[1][2] += av.y * bv.z; acc[1][3] += av.y * bv.w;
      acc[2][0] += av.z * bv.x; acc[2][1] += av.z * bv.y; acc[2][2] += av.z * bv.z; acc[2][3] += av.z * bv.w;
      acc[3][0] += av.w * bv.x; acc[3][1] += av.w * bv.y; acc[3][2] += av.w * bv.z; acc[3][3] += av.w * bv.w;
    }
    __syncthreads();
  }
  const int cc = col0 + (tx << 2);
  float4 bi = *(const float4*)&bias[cc];
  unsigned short* dst;
  int ccl;
  float sc = 1.0f;
  if (cc < 256)      { dst = Qb; ccl = cc;       sc = 0.0625f; }
  else if (cc < 512) { dst = Kb; ccl = cc - 256; }
  else               { dst = Vf; ccl = cc - 512; }
#pragma unroll
  for (int i = 0; i < 4; ++i) {
    int r = row0 + (ty << 2) + i;
    u16x4 h;
    h[0] = f2bf((acc[i][0] + bi.x) * sc);
    h[1] = f2bf((acc[i][1] + bi.y) * sc);
    h[2] = f2bf((acc[i][2] + bi.z) * sc);
    h[3] = f2bf((acc[i][3] + bi.w) * sc);
    *(u16x4*)&dst[(size_t)r * 256 + ccl] = h;
  }
}

// ---------------- V transpose: Vf[b][t][256] -> Vt[b][256][1024] (bf16) ----------------
__global__ __launch_bounds__(256) void vtrans(const unsigned short* __restrict__ Vf,
                                              unsigned short* __restrict__ Vt) {
  __shared__ unsigned short TL[256][72];  // 144B row stride, 16B aligned
  const int b = blockIdx.y;
  const int t0 = blockIdx.x * 64;
  const int tid = threadIdx.x;
  for (int c = tid; c < 2048; c += 256) {  // 64 rows x 32 chunks of 8
    int r = c >> 5, ch = c & 31;
    u16x8 v = *(const u16x8*)&Vf[((size_t)b * 1024 + t0 + r) * 256 + ch * 8];
#pragma unroll
    for (int i = 0; i < 8; ++i) TL[ch * 8 + i][r] = v[i];
  }
  __syncthreads();
  for (int c = tid; c < 2048; c += 256) {  // 256 d-rows x 8 chunks of 8
    int d = c >> 3, ch = c & 7;
    u16x8 v = *(const u16x8*)&TL[d][ch * 8];
    *(u16x8*)&Vt[((size_t)b * 256 + d) * 1024 + t0 + ch * 8] = v;
  }
}

// ---------------- bf16 MFMA causal flash attention ----------------
// grid (16, 32): 64-query tiles (heavy tiles launched first), 4 waves x 16 q-rows.
// Qb/Kb: [b][t][256] bf16 (Q pre-scaled 1/16). Vt: [b][256][1024] bf16. Out ao fp32.
__global__ __launch_bounds__(256) void attn_kernel(const unsigned short* __restrict__ Qb,
                                                   const unsigned short* __restrict__ Kb,
                                                   const unsigned short* __restrict__ Vt,
                                                   float* __restrict__ ao) {
  const int qt = 15 - blockIdx.x;    // heavy first
  const int b = blockIdx.y;
  const int tid = threadIdx.x;
  const int w = tid >> 6, lane = tid & 63;
  const int lo = lane & 15, quad = lane >> 4;

  __shared__ unsigned short Ks[32][264];   // 528B stride: 2-way bank alias only
  __shared__ unsigned short Vs[256][40];   // 80B stride
  __shared__ unsigned short Ps[4][16][40];

  const int q0 = qt * 64;
  const int qr0 = q0 + w * 16;

  // Q fragments: A-layout, m=lo, k=quad*8+j per 32-chunk
  s16x8 qf[8];
  const size_t qbase = ((size_t)b * 1024 + qr0 + lo) * 256;
#pragma unroll
  for (int kc = 0; kc < 8; ++kc)
    qf[kc] = *(const s16x8*)&Qb[qbase + kc * 32 + quad * 8];

  f32x4 O[16];
#pragma unroll
  for (int i = 0; i < 16; ++i) O[i] = (f32x4){0.f, 0.f, 0.f, 0.f};
  float m_i[4] = {-1e30f, -1e30f, -1e30f, -1e30f};
  float l_i[4] = {0.f, 0.f, 0.f, 0.f};

  const int ktmax = 2 * qt + 1;
  for (int kt = 0; kt <= ktmax; ++kt) {
    const int k0 = kt * 32;
    __syncthreads();  // prior tile's LDS reads complete
    // stage K tile [32][256]
    for (int c = tid; c < 1024; c += 256) {
      int r = c >> 5, col = (c & 31) * 8;
      *(u16x8*)&Ks[r][col] = *(const u16x8*)&Kb[((size_t)b * 1024 + k0 + r) * 256 + col];
    }
    // stage V^T tile [256][32]
    for (int c = tid; c < 1024; c += 256) {
      int d = c >> 2, col = (c & 3) * 8;
      *(u16x8*)&Vs[d][col] = *(const u16x8*)&Vt[((size_t)b * 256 + d) * 1024 + k0 + col];
    }
    __syncthreads();

    if (k0 <= qr0 + 15) {  // wave-uniform: skip fully-masked tiles
      // S = Q K^T : two 16x16 n-tiles
      f32x4 s0 = {0.f, 0.f, 0.f, 0.f}, s1 = {0.f, 0.f, 0.f, 0.f};
#pragma unroll
      for (int kc = 0; kc < 8; ++kc) {
        s16x8 kf0 = *(const s16x8*)&Ks[lo][kc * 32 + quad * 8];
        s16x8 kf1 = *(const s16x8*)&Ks[16 + lo][kc * 32 + quad * 8];
        s0 = __builtin_amdgcn_mfma_f32_16x16x32_bf16(qf[kc], kf0, s0, 0, 0, 0);
        s1 = __builtin_amdgcn_mfma_f32_16x16x32_bf16(qf[kc], kf1, s1, 0, 0, 0);
      }
      // causal mask (C-layout: row q = qr0+quad*4+i, col key = k0+{lo, 16+lo})
      if (k0 + 31 > qr0) {
#pragma unroll
        for (int i = 0; i < 4; ++i) {
          int q = qr0 + quad * 4 + i;
          if (k0 + lo > q) s0[i] = -1e30f;
          if (k0 + 16 + lo > q) s1[i] = -1e30f;
        }
      }
      // online softmax per row (16 lanes of a quad share a row)
      float al[4];
#pragma unroll
      for (int i = 0; i < 4; ++i) {
        float mx = fmaxf(s0[i], s1[i]);
        mx = fmaxf(mx, __shfl_xor(mx, 1));
        mx = fmaxf(mx, __shfl_xor(mx, 2));
        mx = fmaxf(mx, __shfl_xor(mx, 4));
        mx = fmaxf(mx, __shfl_xor(mx, 8));
        float mnew = fmaxf(m_i[i], mx);
        al[i] = __expf(m_i[i] - mnew);
        m_i[i] = mnew;
        float p0 = __expf(s0[i] - mnew);
        float p1 = __expf(s1[i] - mnew);
        float rs = p0 + p1;
        rs += __shfl_xor(rs, 1);
        rs += __shfl_xor(rs, 2);
        rs += __shfl_xor(rs, 4);
        rs += __shfl_xor(rs, 8);
        l_i[i] = l_i[i] * al[i] + rs;
        Ps[w][quad * 4 + i][lo] = f2bf(p0);
        Ps[w][quad * 4 + i][16 + lo] = f2bf(p1);
      }
      // rescale O
#pragma unroll
      for (int nt = 0; nt < 16; ++nt) {
        O[nt][0] *= al[0]; O[nt][1] *= al[1];
        O[nt][2] *= al[2]; O[nt][3] *= al[3];
      }
      // P back in A-layout (wave-local LDS round-trip; compiler inserts lgkmcnt)
      s16x8 pf = *(const s16x8*)&Ps[w][lo][quad * 8];
#pragma unroll
      for (int nt = 0; nt < 16; ++nt) {
        s16x8 vf = *(const s16x8*)&Vs[nt * 16 + lo][quad * 8];
        O[nt] = __builtin_amdgcn_mfma_f32_16x16x32_bf16(pf, vf, O[nt], 0, 0, 0);
      }
    }
  }

  float inv[4];
#pragma unroll
  for (int i = 0; i < 4; ++i) inv[i] = 1.f / l_i[i];
#pragma unroll
  for (int nt = 0; nt < 16; ++nt) {
#pragma unroll
    for (int i = 0; i < 4; ++i) {
      ao[((size_t)b * 1024 + qr0 + quad * 4 + i) * 256 + nt * 16 + lo] = O[nt][i] * inv[i];
    }
  }
}

// ---------------- Generic fp32 GEMM + bias (W_out, head) ----------------
__global__ __launch_bounds__(256) void gemm_bias(const float* __restrict__ A,
                                                 const float* __restrict__ Bm,
                                                 const float* __restrict__ bias,
                                                 float* __restrict__ C,
                                                 int M, int N, int K) {
  constexpr int BK = 16;
  __shared__ float As[BK][64 + 4];
  __shared__ float Bs[BK][64 + 4];
  const int t = threadIdx.x;
  const int row0 = blockIdx.y * 64;
  const int col0 = blockIdx.x * 64;
  const int tx = t & 15, ty = t >> 4;
  const int ar = t >> 2, ak = (t & 3) << 2;
  const int bk = t >> 4, bc = (t & 15) << 2;
  float acc[4][4] = {};
  for (int k0 = 0; k0 < K; k0 += BK) {
    float4 a4 = *(const float4*)&A[(size_t)(row0 + ar) * K + k0 + ak];
    float4 b4 = make_float4(0.f, 0.f, 0.f, 0.f);
    if (col0 + bc < N) b4 = *(const float4*)&Bm[(size_t)(k0 + bk) * N + col0 + bc];
    As[ak + 0][ar] = a4.x; As[ak + 1][ar] = a4.y; As[ak + 2][ar] = a4.z; As[ak + 3][ar] = a4.w;
    *(float4*)&Bs[bk][bc] = b4;
    __syncthreads();
#pragma unroll
    for (int k = 0; k < BK; ++k) {
      float4 av = *(const float4*)&As[k][ty << 2];
      float4 bv = *(const float4*)&Bs[k][tx << 2];
      acc[0][0] += av.x * bv.x; acc[0][1] += av.x * bv.y; acc[0][2] += av.x * bv.z; acc[0][3] += av.x * bv.w;
      acc[1][0] += av.y * bv.x; acc[1][1] += av.y * bv.y; acc[1][2] += av.y * bv.z; acc[1][3] += av.y * bv.w;
      acc[2][0] += av.z * bv.x; acc[2][1] += av.z * bv.y; acc[2][2] += av.z * bv.z; acc[2][3] += av.z * bv.w;
      acc[3][0] += av.w * bv.x; acc[3][1] += av.w * bv.y; acc[3][2] += av.w * bv.z; acc[3][3] += av.w * bv.w;
    }
    __syncthreads();
  }
  const int cc = col0 + (tx << 2);
  if (cc < N) {
    float4 bi = *(const float4*)&bias[cc];
#pragma unroll
    for (int i = 0; i < 4; ++i) {
      int r = row0 + (ty << 2) + i;
      float4 o = make_float4(acc[i][0] + bi.x, acc[i][1] + bi.y,
                             acc[i][2] + bi.z, acc[i][3] + bi.w);
      *(float4*)&C[(size_t)r * N + cc] = o;
    }
  }
}

// ---------------- Next-patch MSE ----------------
__global__ __launch_bounds__(256) void loss_kernel(const float* __restrict__ pred,
                                                   const float* __restrict__ xn,
                                                   float* __restrict__ lsum) {
  const int total = B_SZ * (T_SZ - 1) * PS_SZ;
  float acc = 0.f;
  for (int idx = blockIdx.x * blockDim.x + threadIdx.x; idx < total;
       idx += gridDim.x * blockDim.x) {
    int p = idx & 31;
    int rem = idx >> 5;
    int tt = rem % (T_SZ - 1);
    int b = rem / (T_SZ - 1);
    float pr = pred[((size_t)b * T_SZ + tt) * PS_SZ + p];
    float tg = xn[(size_t)b * L_SZ + (tt + 1) * PS_SZ + p];
    float d = pr - tg;
    acc += d * d;
  }
#pragma unroll
  for (int off = 32; off >= 1; off >>= 1) acc += __shfl_down(acc, off);
  __shared__ float red[4];
  const int lane = threadIdx.x & 63, wid = threadIdx.x >> 6;
  if (lane == 0) red[wid] = acc;
  __syncthreads();
  if (threadIdx.x == 0) atomicAdd(lsum, red[0] + red[1] + red[2] + red[3]);
}

__global__ void finalize_kernel(const float* __restrict__ lsum, float* __restrict__ out) {
  out[0] = lsum[0] * (1.f / (float)(B_SZ * (T_SZ - 1) * PS_SZ));
}

extern "C" void kernel_launch(void* const* d_in, const int* in_sizes, int n_in,
                              void* d_out, int out_size, void* d_ws, size_t ws_size,
                              hipStream_t stream) {
  const float* x      = (const float*)d_in[0];
  const float* W_proj = (const float*)d_in[1];
  const float* b_proj = (const float*)d_in[2];
  const float* W_qkv  = (const float*)d_in[3];
  const float* b_qkv  = (const float*)d_in[4];
  const float* W_out  = (const float*)d_in[5];
  const float* b_out  = (const float*)d_in[6];
  const float* W_head = (const float*)d_in[7];
  const float* b_head = (const float*)d_in[8];
  float* out = (float*)d_out;

  char* ws = (char*)d_ws;
  float*          xn   = (float*)(ws);                       // [0,4M) fp32
  unsigned short* Qb   = (unsigned short*)(ws + (4ull  << 20));  // [4M,20M) bf16
  unsigned short* Kb   = (unsigned short*)(ws + (20ull << 20));  // [20M,36M)
  unsigned short* Vf   = (unsigned short*)(ws + (36ull << 20));  // [36M,52M)
  unsigned short* Vt   = (unsigned short*)(ws + (52ull << 20));  // [52M,68M)
  float*          ao   = (float*)(ws + (68ull << 20));       // [68M,100M) fp32
  float*          o2   = (float*)(ws + (4ull  << 20));       // reuse Qb/Kb (dead after attn)
  float*          pred = (float*)(ws + (36ull << 20));       // reuse Vf (dead after vtrans)
  float*          Wcb  = (float*)(ws + (100ull << 20));      // 33x768 folded W+b
  float*          lsum = (float*)(ws + (100ull << 20) + 33ull * 768ull * 4ull);

  hipMemsetAsync(lsum, 0, sizeof(float), stream);
  norm_kernel<<<32, 1024, 0, stream>>>(x, xn);
  wc_kernel<<<(33 * 768 + 255) / 256, 256, 0, stream>>>(W_proj, b_proj, W_qkv, b_qkv, Wcb);
  gemm_qkv<<<dim3(12, 512), 256, 0, stream>>>(xn, Wcb, Wcb + 32 * 768, Qb, Kb, Vf);
  vtrans<<<dim3(16, 32), 256, 0, stream>>>(Vf, Vt);
  attn_kernel<<<dim3(16, 32), 256, 0, stream>>>(Qb, Kb, Vt, ao);
  gemm_bias<<<dim3(4, 512), 256, 0, stream>>>(ao, W_out, b_out, o2, 32768, 256, 256);
  gemm_bias<<<dim3(1, 512), 256, 0, stream>>>(o2, W_head, b_head, pred, 32768, 32, 256);
  loss_kernel<<<256, 256, 0, stream>>>(pred, xn, lsum);
  finalize_kernel<<<1, 1, 0, stream>>>(lsum, out);
}

// Round 3
// 284.336 us; speedup vs baseline: 6.9141x; 1.3425x over previous
//
#include <hip/hip_runtime.h>
#include <math.h>

#define B_SZ 32
#define L_SZ 32768
#define T_SZ 1024
#define PS_SZ 32
#define D_SZ 256

typedef float f32x4 __attribute__((ext_vector_type(4)));
typedef short s16x8 __attribute__((ext_vector_type(8)));
typedef unsigned short u16x8 __attribute__((ext_vector_type(8)));
typedef unsigned short u16x4 __attribute__((ext_vector_type(4)));

__device__ __forceinline__ unsigned short f2bf(float f) {
  union { float f; unsigned int u; } v; v.f = f;
  unsigned int r = v.u + 0x7FFFu + ((v.u >> 16) & 1u);
  return (unsigned short)(r >> 16);
}

// async global->LDS 16B: per-lane global addr, wave-uniform LDS base + lane*16
__device__ __forceinline__ void g2l16(const unsigned short* g, unsigned short* l) {
  __builtin_amdgcn_global_load_lds(
      (const __attribute__((address_space(1))) unsigned int*)g,
      (__attribute__((address_space(3))) unsigned int*)l, 16, 0, 0);
}

// ---------------- InstanceNorm (ddof=1) -> xn fp32 + xbf bf16 ----------------
__global__ __launch_bounds__(1024) void norm_kernel(const float* __restrict__ x,
                                                    float* __restrict__ xn,
                                                    unsigned short* __restrict__ xbf) {
  const int b = blockIdx.x;
  const int t = threadIdx.x;
  const float* row = x + (size_t)b * L_SZ;
  float* orow = xn + (size_t)b * L_SZ;
  unsigned short* brow = xbf + (size_t)b * L_SZ;
  float v[32];
  float s = 0.f, ss = 0.f;
#pragma unroll
  for (int i = 0; i < 8; ++i) {
    float4 f = *(const float4*)&row[i * 4096 + t * 4];
    v[i * 4 + 0] = f.x; v[i * 4 + 1] = f.y; v[i * 4 + 2] = f.z; v[i * 4 + 3] = f.w;
    s += f.x + f.y + f.z + f.w;
    ss += f.x * f.x + f.y * f.y + f.z * f.z + f.w * f.w;
  }
#pragma unroll
  for (int off = 32; off >= 1; off >>= 1) {
    s += __shfl_down(s, off);
    ss += __shfl_down(ss, off);
  }
  __shared__ float red_s[16], red_ss[16];
  __shared__ float sh_mean, sh_inv;
  const int wid = t >> 6, lane = t & 63;
  if (lane == 0) { red_s[wid] = s; red_ss[wid] = ss; }
  __syncthreads();
  if (t == 0) {
    float S = 0.f, SS = 0.f;
    for (int i = 0; i < 16; ++i) { S += red_s[i]; SS += red_ss[i]; }
    float mean = S * (1.f / (float)L_SZ);
    float var = (SS - S * mean) * (1.f / (float)(L_SZ - 1));
    sh_mean = mean;
    sh_inv = 1.f / (sqrtf(var) + 1e-5f);
  }
  __syncthreads();
  const float mean = sh_mean, inv = sh_inv;
#pragma unroll
  for (int i = 0; i < 8; ++i) {
    float4 f;
    f.x = (v[i * 4 + 0] - mean) * inv;
    f.y = (v[i * 4 + 1] - mean) * inv;
    f.z = (v[i * 4 + 2] - mean) * inv;
    f.w = (v[i * 4 + 3] - mean) * inv;
    *(float4*)&orow[i * 4096 + t * 4] = f;
    u16x4 h; h[0] = f2bf(f.x); h[1] = f2bf(f.y); h[2] = f2bf(f.z); h[3] = f2bf(f.w);
    *(u16x4*)&brow[i * 4096 + t * 4] = h;
  }
}

// ---------------- Fold W_proj@W_qkv + bias; also B^T bf16 for MFMA ----------------
__global__ void wc_kernel(const float* __restrict__ Wp, const float* __restrict__ bp,
                          const float* __restrict__ Wq, const float* __restrict__ bq,
                          float* __restrict__ Wcb, unsigned short* __restrict__ WqT) {
  int idx = blockIdx.x * 256 + threadIdx.x;
  if (idx >= 33 * 768) return;
  int p = idx / 768, j = idx % 768;
  const float* arow = (p < 32) ? (Wp + p * 256) : bp;
  float acc = (p < 32) ? 0.f : bq[j];
  for (int d = 0; d < 256; ++d) acc += arow[d] * Wq[d * 768 + j];
  Wcb[idx] = acc;
  if (p < 32) WqT[j * 32 + p] = f2bf(acc);
}

// ---------------- Fold W_out@W_head -> WfT[32][256] bf16, bias fold fp32 ----------------
__global__ void wf_kernel(const float* __restrict__ Wo, const float* __restrict__ bo,
                          const float* __restrict__ Wh, const float* __restrict__ bh,
                          unsigned short* __restrict__ WfT, float* __restrict__ bfp) {
  int idx = blockIdx.x * 256 + threadIdx.x;
  if (idx < 8192) {
    int p = idx >> 8, d = idx & 255;
    float acc = 0.f;
    for (int e = 0; e < 256; ++e) acc += Wo[d * 256 + e] * Wh[e * 32 + p];
    WfT[p * 256 + d] = f2bf(acc);
  } else if (idx < 8224) {
    int p = idx - 8192;
    float acc = bh[p];
    for (int e = 0; e < 256; ++e) acc += bo[e] * Wh[e * 32 + p];
    bfp[p] = acc;
  }
}

// ---------------- qkv via MFMA: [32768,32]bf16 @ [32,768]bf16, K=32 = one k-step ----------------
__global__ __launch_bounds__(256) void gemm_qkv_mfma(const unsigned short* __restrict__ xbf,
                                                     const unsigned short* __restrict__ WqT,
                                                     const float* __restrict__ biasq,
                                                     unsigned short* __restrict__ Qb,
                                                     unsigned short* __restrict__ Kb,
                                                     unsigned short* __restrict__ Vf) {
  const int tid = threadIdx.x;
  const int w = tid >> 6, lane = tid & 63;
  const int lo = lane & 15, quad = lane >> 4;
  const int mbase = blockIdx.x * 128 + w * 32;
  // A-frags: A[m=lo][k=quad*8+j], K=32
  s16x8 af0 = *(const s16x8*)&xbf[(size_t)(mbase + lo) * 32 + quad * 8];
  s16x8 af1 = *(const s16x8*)&xbf[(size_t)(mbase + 16 + lo) * 32 + quad * 8];
#pragma unroll 4
  for (int nt = 0; nt < 48; ++nt) {
    s16x8 bf = *(const s16x8*)&WqT[(size_t)(nt * 16 + lo) * 32 + quad * 8];
    f32x4 c0 = {0.f, 0.f, 0.f, 0.f}, c1 = {0.f, 0.f, 0.f, 0.f};
    c0 = __builtin_amdgcn_mfma_f32_16x16x32_bf16(af0, bf, c0, 0, 0, 0);
    c1 = __builtin_amdgcn_mfma_f32_16x16x32_bf16(af1, bf, c1, 0, 0, 0);
    const int col = nt * 16 + lo;
    const float bi = biasq[col];
    unsigned short* dst; int ccl; float sc = 1.0f;
    if (col < 256)      { dst = Qb; ccl = col;       sc = 0.0625f; }
    else if (col < 512) { dst = Kb; ccl = col - 256; }
    else                { dst = Vf; ccl = col - 512; }
#pragma unroll
    for (int i = 0; i < 4; ++i) {
      dst[(size_t)(mbase + quad * 4 + i) * 256 + ccl]      = f2bf((c0[i] + bi) * sc);
      dst[(size_t)(mbase + 16 + quad * 4 + i) * 256 + ccl] = f2bf((c1[i] + bi) * sc);
    }
  }
}

// ---------------- V transpose: Vf[b][t][256] -> Vt[b][256][1024] (bf16) ----------------
__global__ __launch_bounds__(256) void vtrans(const unsigned short* __restrict__ Vf,
                                              unsigned short* __restrict__ Vt) {
  __shared__ unsigned short TL[256][72];
  const int b = blockIdx.y;
  const int t0 = blockIdx.x * 64;
  const int tid = threadIdx.x;
  for (int c = tid; c < 2048; c += 256) {
    int r = c >> 5, ch = c & 31;
    u16x8 v = *(const u16x8*)&Vf[((size_t)b * 1024 + t0 + r) * 256 + ch * 8];
#pragma unroll
    for (int i = 0; i < 8; ++i) TL[ch * 8 + i][r] = v[i];
  }
  __syncthreads();
  for (int c = tid; c < 2048; c += 256) {
    int d = c >> 3, ch = c & 7;
    u16x8 v = *(const u16x8*)&TL[d][ch * 8];
    *(u16x8*)&Vt[((size_t)b * 256 + d) * 1024 + t0 + ch * 8] = v;
  }
}

// ---------------- Fused flash attention + out/head-proj + MSE loss ----------------
// grid (32 b, 16 qt) -> block id%8 = b%8 keeps a batch's K/V on one XCD.
// 2 waves x 32 q-rows; 64-key tiles; global_load_lds staging; swizzled LDS images.
__global__ __launch_bounds__(128, 1) void attn_kernel(const unsigned short* __restrict__ Qb,
                                                      const unsigned short* __restrict__ Kb,
                                                      const unsigned short* __restrict__ Vt,
                                                      const unsigned short* __restrict__ WfT,
                                                      const float* __restrict__ bfp,
                                                      const float* __restrict__ xn,
                                                      float* __restrict__ lsum) {
  const int b = blockIdx.x;
  const int qt = 15 - (int)blockIdx.y;  // heavy-first
  const int tid = threadIdx.x;
  const int w = tid >> 6, lane = tid & 63;
  const int lo = lane & 15, quad = lane >> 4;
  const int lo7 = lo & 7;

  __shared__ unsigned short KV[32768];        // Ks [0,16384) , Vs [16384,32768) shorts
  __shared__ unsigned short Ps[2][32][72];
  __shared__ float lred[2];
  unsigned short* Ks = KV;
  unsigned short* Vs = KV + 16384;

  const int q0 = qt * 64;
  const int qr0 = q0 + w * 32;               // wave's 32 q-rows

  // Q fragments (A-layout): qf[mt][kc], rows qr0+mt*16+lo, k = kc*32+quad*8+j
  s16x8 qf[2][8];
#pragma unroll
  for (int mt = 0; mt < 2; ++mt) {
    const size_t qb = ((size_t)b * 1024 + qr0 + mt * 16 + lo) * 256;
#pragma unroll
    for (int kc = 0; kc < 8; ++kc) qf[mt][kc] = *(const s16x8*)&Qb[qb + kc * 32 + quad * 8];
  }

  f32x4 O[2][16];
#pragma unroll
  for (int mt = 0; mt < 2; ++mt)
#pragma unroll
    for (int nt = 0; nt < 16; ++nt) O[mt][nt] = (f32x4){0.f, 0.f, 0.f, 0.f};
  f32x4 Ol[2] = {{0.f, 0.f, 0.f, 0.f}, {0.f, 0.f, 0.f, 0.f}};
  float m_i[2][4] = {{-1e30f, -1e30f, -1e30f, -1e30f}, {-1e30f, -1e30f, -1e30f, -1e30f}};

  s16x8 ones;
#pragma unroll
  for (int j = 0; j < 8; ++j) ones[j] = (short)0x3F80;  // bf16 1.0

  for (int kt = 0; kt <= qt; ++kt) {
    const int k0 = kt * 64;
    __syncthreads();  // prev tile fully consumed
    // ---- stage K: image Ks[key][c16'] , c16' low3 = c16 ^ (key&7) ----
#pragma unroll
    for (int ri = 0; ri < 16; ++ri) {
      const int sbase = (w * 16 + ri) * 64;
      const int s = sbase + lane;
      const int key = s >> 5, c16p = s & 31;
      const int c16 = (c16p & 24) | ((c16p & 7) ^ (key & 7));
      g2l16(&Kb[(((size_t)b * 1024 + k0 + key) << 8) + (c16 << 3)], &Ks[sbase * 8]);
    }
    // ---- stage V^T: image Vs[d][c'] , c' = c ^ (d&7), row=64 shorts ----
#pragma unroll
    for (int ri = 0; ri < 16; ++ri) {
      const int sbase = (w * 16 + ri) * 64;
      const int s = sbase + lane;
      const int d = s >> 3, cp = s & 7;
      const int c = cp ^ (d & 7);
      g2l16(&Vt[(((size_t)b * 256 + d) << 10) + k0 + (c << 3)], &Vs[sbase * 8]);
    }
    __syncthreads();  // vmcnt(0) drained before barrier -> tiles visible

    // ---- S = Q K^T : 2 m-tiles x 4 n-tiles, kf shared across m ----
    f32x4 s[2][4];
#pragma unroll
    for (int mt = 0; mt < 2; ++mt)
#pragma unroll
      for (int nt = 0; nt < 4; ++nt) s[mt][nt] = (f32x4){0.f, 0.f, 0.f, 0.f};
#pragma unroll
    for (int kc = 0; kc < 8; ++kc) {
      const int c16 = kc * 4 + quad;
      const int c16s = (c16 & 24) | ((c16 & 7) ^ lo7);
#pragma unroll
      for (int nt = 0; nt < 4; ++nt) {
        s16x8 kf = *(const s16x8*)&Ks[(nt * 16 + lo) * 256 + c16s * 8];
        s[0][nt] = __builtin_amdgcn_mfma_f32_16x16x32_bf16(qf[0][kc], kf, s[0][nt], 0, 0, 0);
        s[1][nt] = __builtin_amdgcn_mfma_f32_16x16x32_bf16(qf[1][kc], kf, s[1][nt], 0, 0, 0);
      }
    }
    // ---- causal mask: only last tile straddles (k0 == q0 block-aligned) ----
    if (kt == qt) {
#pragma unroll
      for (int mt = 0; mt < 2; ++mt)
#pragma unroll
        for (int i = 0; i < 4; ++i) {
          const int rowg = qr0 + mt * 16 + quad * 4 + i;
#pragma unroll
          for (int nt = 0; nt < 4; ++nt)
            if (k0 + nt * 16 + lo > rowg) s[mt][nt][i] = -1e30f;
        }
    }
    // ---- online softmax (max via shfl; row-sum l via ones-MFMA below) ----
#pragma unroll
    for (int mt = 0; mt < 2; ++mt) {
      float al[4];
#pragma unroll
      for (int i = 0; i < 4; ++i) {
        float mx = fmaxf(fmaxf(s[mt][0][i], s[mt][1][i]), fmaxf(s[mt][2][i], s[mt][3][i]));
        mx = fmaxf(mx, __shfl_xor(mx, 1));
        mx = fmaxf(mx, __shfl_xor(mx, 2));
        mx = fmaxf(mx, __shfl_xor(mx, 4));
        mx = fmaxf(mx, __shfl_xor(mx, 8));
        const float mnew = fmaxf(m_i[mt][i], mx);
        al[i] = __expf(m_i[mt][i] - mnew);
        m_i[mt][i] = mnew;
        const int prow = mt * 16 + quad * 4 + i;
#pragma unroll
        for (int nt = 0; nt < 4; ++nt)
          Ps[w][prow][nt * 16 + lo] = f2bf(__expf(s[mt][nt][i] - mnew));
      }
      Ol[mt][0] *= al[0]; Ol[mt][1] *= al[1]; Ol[mt][2] *= al[2]; Ol[mt][3] *= al[3];
#pragma unroll
      for (int nt = 0; nt < 16; ++nt) {
        O[mt][nt][0] *= al[0]; O[mt][nt][1] *= al[1];
        O[mt][nt][2] *= al[2]; O[mt][nt][3] *= al[3];
      }
    }
    // ---- PV + row-sum(l): P back as A-frags via wave-local LDS ----
#pragma unroll
    for (int kch = 0; kch < 2; ++kch) {
      s16x8 pf0 = *(const s16x8*)&Ps[w][lo][kch * 32 + quad * 8];
      s16x8 pf1 = *(const s16x8*)&Ps[w][16 + lo][kch * 32 + quad * 8];
      Ol[0] = __builtin_amdgcn_mfma_f32_16x16x32_bf16(pf0, ones, Ol[0], 0, 0, 0);
      Ol[1] = __builtin_amdgcn_mfma_f32_16x16x32_bf16(pf1, ones, Ol[1], 0, 0, 0);
#pragma unroll
      for (int nt = 0; nt < 16; ++nt) {
        const int d = nt * 16 + lo;
        const int cs = (kch * 4 + quad) ^ lo7;
        s16x8 vf = *(const s16x8*)&Vs[d * 64 + cs * 8];
        O[0][nt] = __builtin_amdgcn_mfma_f32_16x16x32_bf16(pf0, vf, O[0][nt], 0, 0, 0);
        O[1][nt] = __builtin_amdgcn_mfma_f32_16x16x32_bf16(pf1, vf, O[1][nt], 0, 0, 0);
      }
    }
  }

  // ---- normalize O and round-trip to LDS (overlay on Ks region) as bf16 ----
  __syncthreads();  // all waves done with Ks/Vs
  unsigned short* OL = KV;  // [64 rows][256], swizzled like Ks
#pragma unroll
  for (int mt = 0; mt < 2; ++mt) {
    f32x4 inv;
#pragma unroll
    for (int i = 0; i < 4; ++i) inv[i] = 1.f / Ol[mt][i];
#pragma unroll
    for (int nt = 0; nt < 16; ++nt) {
      const int col = nt * 16 + lo;
      const int c16 = col >> 3;
#pragma unroll
      for (int i = 0; i < 4; ++i) {
        const int r = w * 32 + mt * 16 + quad * 4 + i;
        const int c16s = (c16 & 24) | ((c16 & 7) ^ (r & 7));
        OL[r * 256 + c16s * 8 + (col & 7)] = f2bf(O[mt][nt][i] * inv[i]);
      }
    }
  }
  __syncthreads();

  // ---- pred = O @ WfT^T + bfp ; fused next-patch MSE ----
  s16x8 bfr[2][8];
#pragma unroll
  for (int nt = 0; nt < 2; ++nt)
#pragma unroll
    for (int kc = 0; kc < 8; ++kc)
      bfr[nt][kc] = *(const s16x8*)&WfT[(size_t)(nt * 16 + lo) * 256 + kc * 32 + quad * 8];
  const float badd = bfp[lo];  // col p = nt*16+lo, nt<2; p<32 -> bfp[nt*16+lo]
  const float badd1 = bfp[16 + lo];
  float lacc = 0.f;
#pragma unroll
  for (int pmt = 0; pmt < 2; ++pmt) {
    const int rA = w * 32 + pmt * 16 + lo;
    s16x8 af[8];
#pragma unroll
    for (int kc = 0; kc < 8; ++kc) {
      const int c16 = kc * 4 + quad;
      const int c16s = (c16 & 24) | ((c16 & 7) ^ (rA & 7));
      af[kc] = *(const s16x8*)&OL[rA * 256 + c16s * 8];
    }
#pragma unroll
    for (int nt = 0; nt < 2; ++nt) {
      f32x4 acc = {0.f, 0.f, 0.f, 0.f};
#pragma unroll
      for (int kc = 0; kc < 8; ++kc)
        acc = __builtin_amdgcn_mfma_f32_16x16x32_bf16(af[kc], bfr[nt][kc], acc, 0, 0, 0);
      const float ba = nt == 0 ? badd : badd1;
      const int p = nt * 16 + lo;
#pragma unroll
      for (int i = 0; i < 4; ++i) {
        const int t = q0 + w * 32 + pmt * 16 + quad * 4 + i;
        if (t < 1023) {
          const float pr = acc[i] + ba;
          const float tg = xn[(size_t)b * L_SZ + (t + 1) * 32 + p];
          const float d = pr - tg;
          lacc += d * d;
        }
      }
    }
  }
#pragma unroll
  for (int off = 32; off >= 1; off >>= 1) lacc += __shfl_down(lacc, off);
  if (lane == 0) lred[w] = lacc;
  __syncthreads();
  if (tid == 0) atomicAdd(lsum, lred[0] + lred[1]);
}

__global__ void finalize_kernel(const float* __restrict__ lsum, float* __restrict__ out) {
  out[0] = lsum[0] * (1.f / (float)(B_SZ * (T_SZ - 1) * PS_SZ));
}

extern "C" void kernel_launch(void* const* d_in, const int* in_sizes, int n_in,
                              void* d_out, int out_size, void* d_ws, size_t ws_size,
                              hipStream_t stream) {
  const float* x      = (const float*)d_in[0];
  const float* W_proj = (const float*)d_in[1];
  const float* b_proj = (const float*)d_in[2];
  const float* W_qkv  = (const float*)d_in[3];
  const float* b_qkv  = (const float*)d_in[4];
  const float* W_out  = (const float*)d_in[5];
  const float* b_out  = (const float*)d_in[6];
  const float* W_head = (const float*)d_in[7];
  const float* b_head = (const float*)d_in[8];
  float* out = (float*)d_out;

  char* ws = (char*)d_ws;
  float*          xn  = (float*)(ws);                          // [0,4M) fp32
  unsigned short* xbf = (unsigned short*)(ws + (4ull << 20));  // [4M,6M) bf16
  unsigned short* Qb  = (unsigned short*)(ws + (8ull << 20));  // 16MB
  unsigned short* Kb  = (unsigned short*)(ws + (26ull << 20));
  unsigned short* Vf  = (unsigned short*)(ws + (44ull << 20));
  unsigned short* Vt  = (unsigned short*)(ws + (62ull << 20));
  char* tail = ws + (80ull << 20);
  float*          Wcb  = (float*)(tail);                       // 33x768 fp32
  unsigned short* WqT  = (unsigned short*)(tail + (128ull << 10));  // 768x32 bf16
  unsigned short* WfT  = (unsigned short*)(tail + (192ull << 10));  // 32x256 bf16
  float*          bfp  = (float*)(tail + (224ull << 10));      // 32 fp32
  float*          lsum = (float*)(tail + (224ull << 10) + 512);

  hipMemsetAsync(lsum, 0, sizeof(float), stream);
  norm_kernel<<<32, 1024, 0, stream>>>(x, xn, xbf);
  wc_kernel<<<99, 256, 0, stream>>>(W_proj, b_proj, W_qkv, b_qkv, Wcb, WqT);
  wf_kernel<<<33, 256, 0, stream>>>(W_out, b_out, W_head, b_head, WfT, bfp);
  gemm_qkv_mfma<<<256, 256, 0, stream>>>(xbf, WqT, Wcb + 32 * 768, Qb, Kb, Vf);
  vtrans<<<dim3(16, 32), 256, 0, stream>>>(Vf, Vt);
  attn_kernel<<<dim3(32, 16), 128, 0, stream>>>(Qb, Kb, Vt, WfT, bfp, xn, lsum);
  finalize_kernel<<<1, 1, 0, stream>>>(lsum, out);
}